// Round 8
// baseline (439.857 us; speedup 1.0000x reference)
//
#include <hip/hip_runtime.h>
#include <hip/hip_bf16.h>

typedef __hip_bfloat16 bf16;
typedef __attribute__((ext_vector_type(8))) short short8;
typedef __attribute__((ext_vector_type(4))) float f32x4;

#define BB 8
#define QQ 900
#define DD 256
#define NH 8
#define HD 32
#define NPTS 4
#define FFD 1024
#define HH 100
#define WW2 100
#define HWTOT 10000

#define QT 64
#define KTC 128
#define NCHUNK ((QQ + KTC - 1) / KTC)  // 8
#define GQB 8                           // queries per gather block

__device__ inline float tofloat(float x) { return x; }
__device__ inline float tofloat(bf16 x) { return __bfloat162float(x); }
__device__ inline float bf2f(unsigned short u) {
    return __uint_as_float(((unsigned int)u) << 16);
}
__device__ inline void storev(bf16* p, float v) { *p = __float2bfloat16(v); }
__device__ inline void storev(float* p, float v) { *p = v; }
__device__ inline unsigned short f2bu(float v) {
    bf16 t = __float2bfloat16(v);
    return *(unsigned short*)&t;
}

// ---------------- pack kernel: fp32 weights -> bf16 workspace ----------
// wpk (bf16): [ in_proj_w 196608 | out_proj_w 65536 | cout_w 65536 | ffn_w1 262144 |
//   ffn_w2 262144 | vproj_w 65536 | dots_w 32768 ], then dbias fp32[128].
__global__ void pack_kernel(const float* __restrict__ in_proj_w, const float* __restrict__ out_proj_w,
                            const float* __restrict__ cout_w, const float* __restrict__ ffn_w1,
                            const float* __restrict__ ffn_w2, const float* __restrict__ vproj_w,
                            const float* __restrict__ offs_w, const float* __restrict__ attw_w,
                            const float* __restrict__ ref_w, const float* __restrict__ offs_b,
                            const float* __restrict__ attw_b, const float* __restrict__ ref_b,
                            bf16* __restrict__ wpk, float* __restrict__ dbias) {
    const int idx = blockIdx.x * 256 + threadIdx.x;
    const int TOT = 950272 + 128;
    if (idx >= TOT) return;
    if (idx < 196608) {
        wpk[idx] = __float2bfloat16(in_proj_w[idx]);
    } else if (idx < 262144) {
        wpk[idx] = __float2bfloat16(out_proj_w[idx - 196608]);
    } else if (idx < 327680) {
        wpk[idx] = __float2bfloat16(cout_w[idx - 262144]);
    } else if (idx < 589824) {
        wpk[idx] = __float2bfloat16(ffn_w1[idx - 327680]);
    } else if (idx < 851968) {
        wpk[idx] = __float2bfloat16(ffn_w2[idx - 589824]);
    } else if (idx < 917504) {
        wpk[idx] = __float2bfloat16(vproj_w[idx - 851968]);
    } else if (idx < 950272) {
        const int j = idx - 917504;
        const int r = j >> 8, c = j & 255;
        float v = 0.f;
        if (r < 64) v = offs_w[r * 256 + c];
        else if (r < 96) v = attw_w[(r - 64) * 256 + c];
        else if (r < 98) v = ref_w[(r - 96) * 256 + c];
        wpk[idx] = __float2bfloat16(v);
    } else {
        const int j = idx - 950272;
        float v = 0.f;
        if (j < 64) v = offs_b[j];
        else if (j < 96) v = attw_b[j - 64];
        else if (j < 98) v = ref_b[j - 96];
        dbias[j] = v;
    }
}

// ---- staging helpers: 8 contiguous elements -> 8 bf16 in LDS ----
__device__ inline void stage8(unsigned short* dst, const bf16* A, size_t off, bool ok) {
    const uint4 z = {0u, 0u, 0u, 0u};
    *(uint4*)dst = ok ? *(const uint4*)((const unsigned short*)A + off) : z;
}
__device__ inline void stage8(unsigned short* dst, const float* A, size_t off, bool ok) {
    if (ok) {
        const float4 f0 = *(const float4*)(A + off);
        const float4 f1 = *(const float4*)(A + off + 4);
        dst[0] = f2bu(f0.x); dst[1] = f2bu(f0.y); dst[2] = f2bu(f0.z); dst[3] = f2bu(f0.w);
        dst[4] = f2bu(f1.x); dst[5] = f2bu(f1.y); dst[6] = f2bu(f1.z); dst[7] = f2bu(f1.w);
    } else {
        const uint4 z = {0u, 0u, 0u, 0u};
        *(uint4*)dst = z;
    }
}

// ---------------- MFMA GEMM: C[M,N] = act(A[M,K] @ W[N,K]^T + bias) ----------------
// BM=128, BN=64, BK=32; 256 thr = 4 waves; wave owns 32 rows x 64 cols
// (2x4 16x16 tiles, 8 MFMAs per K-step, 6 ds_read_b128).
template <int ACT, typename TA, typename OT>
__global__ __launch_bounds__(256) void gemm_mfma_kernel(const TA* __restrict__ A,
                                                        const bf16* __restrict__ W,
                                                        const float* __restrict__ bias,
                                                        OT* __restrict__ C, int M, int N, int K) {
    __shared__ unsigned short As[128][40];  // pad 40 shorts: 2-way-free banks
    __shared__ unsigned short Bs[64][40];
    const int bm = blockIdx.y * 128, bn = blockIdx.x * 64;
    const int tid = threadIdx.x;
    const int lane = tid & 63, wave = tid >> 6;
    const int l15 = lane & 15, g = lane >> 4;
    const f32x4 zf = {0.f, 0.f, 0.f, 0.f};
    f32x4 acc[2][4];
#pragma unroll
    for (int rt = 0; rt < 2; ++rt)
#pragma unroll
        for (int ct = 0; ct < 4; ++ct) acc[rt][ct] = zf;

    for (int k0 = 0; k0 < K; k0 += 32) {
        __syncthreads();
#pragma unroll
        for (int pass = 0; pass < 2; ++pass) {  // A: 128 rows x 32
            const int c = tid + pass * 256;
            const int r = c >> 2, col = (c & 3) * 8;
            const int arow = bm + r;
            stage8(&As[r][col], A, (size_t)arow * K + k0 + col, arow < M);
        }
        {  // B: 64 rows x 32
            const int r = tid >> 2, col = (tid & 3) * 8;
            const int wrow = bn + r;
            stage8(&Bs[r][col], W, (size_t)wrow * K + k0 + col, wrow < N);
        }
        __syncthreads();
        short8 af[2];
        af[0] = *(const short8*)&As[wave * 32 + l15][g * 8];
        af[1] = *(const short8*)&As[wave * 32 + 16 + l15][g * 8];
#pragma unroll
        for (int ct = 0; ct < 4; ++ct) {
            const short8 bf = *(const short8*)&Bs[ct * 16 + l15][g * 8];
            acc[0][ct] = __builtin_amdgcn_mfma_f32_16x16x32_bf16(af[0], bf, acc[0][ct], 0, 0, 0);
            acc[1][ct] = __builtin_amdgcn_mfma_f32_16x16x32_bf16(af[1], bf, acc[1][ct], 0, 0, 0);
        }
    }
#pragma unroll
    for (int rt = 0; rt < 2; ++rt)
#pragma unroll
        for (int ct = 0; ct < 4; ++ct) {
            const int col = bn + ct * 16 + l15;
            const float bv = bias[col];
#pragma unroll
            for (int r = 0; r < 4; ++r) {
                const int row = bm + wave * 32 + rt * 16 + g * 4 + r;
                if (row < M) {
                    float v = acc[rt][ct][r] + bv;
                    if (ACT == 1) v = fmaxf(v, 0.f);
                    storev(&C[(size_t)row * N + col], v);
                }
            }
        }
}

// ---------------- MFMA flash MHA (unchanged from round 7) ----------------
__global__ __launch_bounds__(256) void mha_mfma_kernel(const bf16* __restrict__ qkv,
                                                       bf16* __restrict__ o) {
    const int qt = blockIdx.x, h = blockIdx.y, b = blockIdx.z;
    const int tid = threadIdx.x;
    const int lane = tid & 63, wave = tid >> 6;
    const int l15 = lane & 15, g = lane >> 4;
    __shared__ unsigned short Kls[KTC][40];
    __shared__ bf16 Vt[HD][136];
    __shared__ bf16 Pls[4][16][136];
    const size_t base = (size_t)b * QQ * 768;
    const int q0 = qt * QT;

    short8 qa = {0, 0, 0, 0, 0, 0, 0, 0};
    {
        const int qg = q0 + wave * 16 + l15;
        if (qg < QQ)
            qa = *(const short8*)(qkv + base + (size_t)qg * 768 + h * HD + g * 8);
    }
    f32x4 accO[2] = {{0.f, 0.f, 0.f, 0.f}, {0.f, 0.f, 0.f, 0.f}};
    float m_run[4], l_run[4];
#pragma unroll
    for (int r = 0; r < 4; ++r) {
        m_run[r] = -1e30f;
        l_run[r] = 0.f;
    }
    const float scale = 0.17677669529663687f;
    const uint4 zero4 = {0u, 0u, 0u, 0u};

    for (int c = 0; c < NCHUNK; ++c) {
        const int k0 = c * KTC;
        __syncthreads();
        {
            const int part = tid & 3, kr = tid >> 2;
#pragma unroll
            for (int pass = 0; pass < 2; ++pass) {
                const int krr = kr + pass * 64;
                const int kg = k0 + krr;
                uint4 kv = (kg < QQ)
                    ? *(const uint4*)(qkv + base + (size_t)kg * 768 + DD + h * HD + part * 8)
                    : zero4;
                *(uint4*)&Kls[krr][part * 8] = kv;
            }
        }
        {
            const int kr = tid >> 1, ch0 = (tid & 1) * 16;
            const int kg = k0 + kr;
            uint4 v0 = zero4, v1 = zero4;
            if (kg < QQ) {
                const bf16* pv = qkv + base + (size_t)kg * 768 + 2 * DD + h * HD + ch0;
                v0 = *(const uint4*)pv;
                v1 = *(const uint4*)(pv + 8);
            }
            const unsigned short* u0 = (const unsigned short*)&v0;
            const unsigned short* u1 = (const unsigned short*)&v1;
#pragma unroll
            for (int j = 0; j < 8; ++j) {
                ((unsigned short*)&Vt[ch0 + j][kr])[0] = u0[j];
                ((unsigned short*)&Vt[ch0 + 8 + j][kr])[0] = u1[j];
            }
        }
        __syncthreads();

        f32x4 s[8];
#pragma unroll
        for (int t = 0; t < 8; ++t) {
            const short8 kb = *(const short8*)&Kls[t * 16 + l15][g * 8];
            const f32x4 z = {0.f, 0.f, 0.f, 0.f};
            s[t] = __builtin_amdgcn_mfma_f32_16x16x32_bf16(qa, kb, z, 0, 0, 0);
        }
        float mx[4] = {-1e30f, -1e30f, -1e30f, -1e30f};
#pragma unroll
        for (int t = 0; t < 8; ++t) {
            const bool cv = (k0 + t * 16 + l15) < QQ;
#pragma unroll
            for (int r = 0; r < 4; ++r) {
                const float v = cv ? s[t][r] * scale : -1e30f;
                s[t][r] = v;
                mx[r] = fmaxf(mx[r], v);
            }
        }
#pragma unroll
        for (int r = 0; r < 4; ++r) {
            mx[r] = fmaxf(mx[r], __shfl_xor(mx[r], 1));
            mx[r] = fmaxf(mx[r], __shfl_xor(mx[r], 2));
            mx[r] = fmaxf(mx[r], __shfl_xor(mx[r], 4));
            mx[r] = fmaxf(mx[r], __shfl_xor(mx[r], 8));
        }
        float alpha[4], rs[4];
#pragma unroll
        for (int r = 0; r < 4; ++r) {
            const float mn = fmaxf(m_run[r], mx[r]);
            alpha[r] = __expf(m_run[r] - mn);
            m_run[r] = mn;
            rs[r] = 0.f;
        }
#pragma unroll
        for (int t = 0; t < 8; ++t) {
#pragma unroll
            for (int r = 0; r < 4; ++r) {
                const float p = __expf(s[t][r] - m_run[r]);
                rs[r] += p;
                Pls[wave][g * 4 + r][t * 16 + l15] = __float2bfloat16(p);
            }
        }
#pragma unroll
        for (int r = 0; r < 4; ++r) {
            rs[r] += __shfl_xor(rs[r], 1);
            rs[r] += __shfl_xor(rs[r], 2);
            rs[r] += __shfl_xor(rs[r], 4);
            rs[r] += __shfl_xor(rs[r], 8);
            l_run[r] = l_run[r] * alpha[r] + rs[r];
        }
#pragma unroll
        for (int t2 = 0; t2 < 2; ++t2)
#pragma unroll
            for (int r = 0; r < 4; ++r) accO[t2][r] *= alpha[r];
#pragma unroll
        for (int s4 = 0; s4 < 4; ++s4) {
            const short8 pa = *(const short8*)&Pls[wave][l15][s4 * 32 + g * 8];
#pragma unroll
            for (int t2 = 0; t2 < 2; ++t2) {
                const short8 vb = *(const short8*)&Vt[t2 * 16 + l15][s4 * 32 + g * 8];
                accO[t2] = __builtin_amdgcn_mfma_f32_16x16x32_bf16(pa, vb, accO[t2], 0, 0, 0);
            }
        }
    }
#pragma unroll
    for (int r = 0; r < 4; ++r) {
        const int row = q0 + wave * 16 + g * 4 + r;
        if (row < QQ) {
            const float inv = 1.f / l_run[r];
#pragma unroll
            for (int t2 = 0; t2 < 2; ++t2) {
                storev(&o[((size_t)b * QQ + row) * DD + h * HD + t2 * 16 + l15],
                       accO[t2][r] * inv);
            }
        }
    }
}

// ---------------- residual + LayerNorm ----------------
template <typename TR, typename TO>
__global__ void add_ln_kernel(const TR* __restrict__ resid, const bf16* __restrict__ y,
                              const float* __restrict__ g, const float* __restrict__ bta,
                              TO* __restrict__ out) {
    const int row = blockIdx.x;
    const int tid = threadIdx.x;
    __shared__ float red[256];
    const size_t idx = (size_t)row * DD + tid;
    float v = tofloat(resid[idx]) + tofloat(y[idx]);
    red[tid] = v;
    __syncthreads();
    for (int s = 128; s > 0; s >>= 1) {
        if (tid < s) red[tid] += red[tid + s];
        __syncthreads();
    }
    const float mean = red[0] * (1.f / DD);
    __syncthreads();
    const float d = v - mean;
    red[tid] = d * d;
    __syncthreads();
    for (int s = 128; s > 0; s >>= 1) {
        if (tid < s) red[tid] += red[tid + s];
        __syncthreads();
    }
    const float rstd = rsqrtf(red[0] * (1.f / DD) + 1e-5f);
    storev(&out[idx], d * rstd * g[tid] + bta[tid]);
}

// ---------------- deformable gather from precomputed val ----------------
// val[b*HWTOT+pos][256] bf16 (= mem@Wv^T+bv). One thread per (q,hp); gathers
// the 32 channels of head h at 4 corners, weights by attw*bilinear*valid,
// LDS-reduce over p, write samp[b,q,256].
__global__ __launch_bounds__(256) void deform_gather_kernel(const float* __restrict__ dots,
                                                            const bf16* __restrict__ val,
                                                            bf16* __restrict__ samp) {
    const int b = blockIdx.y;
    const int q0 = blockIdx.x * GQB;
    const int tid = threadIdx.x;
    const int q = tid >> 5, hp = tid & 31, h = hp >> 2;
    const int qg = q0 + q;
    __shared__ float Gs[GQB][32][36];
    float accv[32];
#pragma unroll
    for (int j = 0; j < 32; ++j) accv[j] = 0.f;

    if (qg < QQ) {
        const float* dr = dots + ((size_t)b * QQ + qg) * 128;
        const float ox = dr[hp * 2], oy = dr[hp * 2 + 1];
        const float ad = dr[64 + hp];
        const float rx = dr[96], ry = dr[97];
        float mx = ad;
        mx = fmaxf(mx, __shfl_xor(mx, 1));
        mx = fmaxf(mx, __shfl_xor(mx, 2));
        const float e = __expf(ad - mx);
        float sm = e;
        sm += __shfl_xor(sm, 1);
        sm += __shfl_xor(sm, 2);
        const float a = e / sm;
        const float refx = 1.f / (1.f + __expf(-rx));
        const float refy = 1.f / (1.f + __expf(-ry));
        const float x = (refx + ox * (1.f / WW2)) * WW2 - 0.5f;
        const float y = (refy + oy * (1.f / HH)) * HH - 0.5f;
        const float x0f = floorf(x), y0f = floorf(y);
        const float lx = x - x0f, ly = y - y0f;
        const int x0 = (int)x0f, y0 = (int)y0f;
        const float cw[4] = {(1 - lx) * (1 - ly), lx * (1 - ly), (1 - lx) * ly, lx * ly};
        const int cx[4] = {x0, x0 + 1, x0, x0 + 1};
        const int cy[4] = {y0, y0, y0 + 1, y0 + 1};
        const bf16* vb = val + (size_t)b * HWTOT * DD + h * HD;
#pragma unroll
        for (int cc = 0; cc < 4; ++cc) {
            const bool valid = cx[cc] >= 0 && cx[cc] < WW2 && cy[cc] >= 0 && cy[cc] < HH;
            const float w = valid ? a * cw[cc] : 0.f;
            if (w != 0.f) {
                const int xi = min(max(cx[cc], 0), WW2 - 1);
                const int yi = min(max(cy[cc], 0), HH - 1);
                const bf16* p = vb + (size_t)(yi * WW2 + xi) * DD;
                const uint4 u0 = *(const uint4*)p;
                const uint4 u1 = *(const uint4*)(p + 8);
                const uint4 u2 = *(const uint4*)(p + 16);
                const uint4 u3 = *(const uint4*)(p + 24);
                const unsigned short* s0 = (const unsigned short*)&u0;
                const unsigned short* s1 = (const unsigned short*)&u1;
                const unsigned short* s2 = (const unsigned short*)&u2;
                const unsigned short* s3 = (const unsigned short*)&u3;
#pragma unroll
                for (int j = 0; j < 8; ++j) {
                    accv[j] += w * bf2f(s0[j]);
                    accv[8 + j] += w * bf2f(s1[j]);
                    accv[16 + j] += w * bf2f(s2[j]);
                    accv[24 + j] += w * bf2f(s3[j]);
                }
            }
        }
    }
#pragma unroll
    for (int j4 = 0; j4 < 8; ++j4) {
        float4 t = {accv[j4 * 4], accv[j4 * 4 + 1], accv[j4 * 4 + 2], accv[j4 * 4 + 3]};
        *(float4*)&Gs[q][hp][j4 * 4] = t;
    }
    __syncthreads();
    {
        const int q2 = tid >> 5, idx5 = tid & 31;
        const int h2 = idx5 >> 2, cg = idx5 & 3;
        if (q0 + q2 < QQ) {
            float s[8] = {0.f, 0.f, 0.f, 0.f, 0.f, 0.f, 0.f, 0.f};
#pragma unroll
            for (int p = 0; p < 4; ++p) {
                const float4 a0 = *(const float4*)&Gs[q2][h2 * 4 + p][cg * 8];
                const float4 a1 = *(const float4*)&Gs[q2][h2 * 4 + p][cg * 8 + 4];
                s[0] += a0.x; s[1] += a0.y; s[2] += a0.z; s[3] += a0.w;
                s[4] += a1.x; s[5] += a1.y; s[6] += a1.z; s[7] += a1.w;
            }
            unsigned short outp[8];
#pragma unroll
            for (int j = 0; j < 8; ++j) outp[j] = f2bu(s[j]);
            bf16* op = samp + ((size_t)b * QQ + q0 + q2) * DD + h2 * HD + cg * 8;
            *(uint4*)op = *(uint4*)outp;
        }
    }
}

extern "C" void kernel_launch(void* const* d_in, const int* in_sizes, int n_in,
                              void* d_out, int out_size, void* d_ws, size_t ws_size,
                              hipStream_t stream) {
    const float* tgt = (const float*)d_in[0];
    const float* memory = (const float*)d_in[1];
    const float* in_proj_w = (const float*)d_in[4];
    const float* in_proj_b = (const float*)d_in[5];
    const float* out_proj_w = (const float*)d_in[6];
    const float* out_proj_b = (const float*)d_in[7];
    const float* norm1_s = (const float*)d_in[8];
    const float* norm1_b = (const float*)d_in[9];
    const float* norm2_s = (const float*)d_in[10];
    const float* norm2_b = (const float*)d_in[11];
    const float* norm3_s = (const float*)d_in[12];
    const float* norm3_b = (const float*)d_in[13];
    const float* vproj_w = (const float*)d_in[14];
    const float* vproj_b = (const float*)d_in[15];
    const float* offs_w = (const float*)d_in[16];
    const float* offs_b = (const float*)d_in[17];
    const float* attw_w = (const float*)d_in[18];
    const float* attw_b = (const float*)d_in[19];
    const float* ref_w = (const float*)d_in[20];
    const float* ref_b = (const float*)d_in[21];
    const float* cout_w = (const float*)d_in[22];
    const float* cout_b = (const float*)d_in[23];
    const float* ffn_w1 = (const float*)d_in[24];
    const float* ffn_b1 = (const float*)d_in[25];
    const float* ffn_w2 = (const float*)d_in[26];
    const float* ffn_b2 = (const float*)d_in[27];

    const int M = BB * QQ;  // 7200
    bf16* ws = (bf16*)d_ws;
    size_t off = 0;
    bf16* qkv = ws + off;  off += (size_t)M * 768;   // 5,529,600
    bf16* o = ws + off;    off += (size_t)M * DD;
    bf16* t1 = ws + off;   off += (size_t)M * DD;
    bf16* tmp = ws + off;  off += (size_t)M * DD;
    bf16* ffh = ws + off;  off += (size_t)M * FFD;   // 7,372,800
    bf16* wpk = ws + off;  off += 950272;
    float* dbias = (float*)(ws + off); off += 256;   // 128 fp32
    bf16* val = ws + off;  off += (size_t)BB * HWTOT * DD;  // 20,480,000
    bf16* samp = o;                     // alias: o dead after out_proj
    bf16* t2n = qkv;                    // alias: qkv dead after mha
    float* dots = (float*)ffh;          // alias: ffh used only after gather

    bf16* w_in = wpk;
    bf16* w_out = wpk + 196608;
    bf16* w_cout = wpk + 262144;
    bf16* w_ffn1 = wpk + 327680;
    bf16* w_ffn2 = wpk + 589824;
    bf16* w_vproj = wpk + 851968;
    bf16* w_dots = wpk + 917504;

    const int MT = (M + 127) / 128;  // 57

    // 0. pack weights to bf16
    pack_kernel<<<(950272 + 128 + 255) / 256, 256, 0, stream>>>(
        in_proj_w, out_proj_w, cout_w, ffn_w1, ffn_w2, vproj_w, offs_w, attw_w, ref_w,
        offs_b, attw_b, ref_b, wpk, dbias);
    // 1. value projection: val = memory @ Wv^T + bv  (fp32 A staged on the fly)
    gemm_mfma_kernel<0, float, bf16><<<dim3(4, (BB * HWTOT + 127) / 128), 256, 0, stream>>>(
        memory, w_vproj, vproj_b, val, BB * HWTOT, DD, DD);
    // 2. QKV projection (fp32 A)
    gemm_mfma_kernel<0, float, bf16><<<dim3(12, MT), 256, 0, stream>>>(tgt, w_in, in_proj_b,
                                                                       qkv, M, 768, DD);
    // 3. self-attention
    mha_mfma_kernel<<<dim3((QQ + QT - 1) / QT, NH, BB), 256, 0, stream>>>(qkv, o);
    // 4. out projection
    gemm_mfma_kernel<0, bf16, bf16><<<dim3(4, MT), 256, 0, stream>>>(o, w_out, out_proj_b,
                                                                     tmp, M, DD, DD);
    // 5. LN1
    add_ln_kernel<float, bf16><<<M, 256, 0, stream>>>(tgt, tmp, norm1_s, norm1_b, t1);
    // 6. deform param dots GEMM -> fp32 [M,128]
    gemm_mfma_kernel<0, bf16, float><<<dim3(2, MT), 256, 0, stream>>>(t1, w_dots, dbias,
                                                                      dots, M, 128, DD);
    // 7. gather from val
    deform_gather_kernel<<<dim3((QQ + GQB - 1) / GQB, BB), 256, 0, stream>>>(dots, val, samp);
    // 8. cross-attn out projection
    gemm_mfma_kernel<0, bf16, bf16><<<dim3(4, MT), 256, 0, stream>>>(samp, w_cout, cout_b,
                                                                     tmp, M, DD, DD);
    // 9. LN2
    add_ln_kernel<bf16, bf16><<<M, 256, 0, stream>>>(t1, tmp, norm2_s, norm2_b, t2n);
    // 10. FFN layer 1 (+ReLU)
    gemm_mfma_kernel<1, bf16, bf16><<<dim3(16, MT), 256, 0, stream>>>(t2n, w_ffn1, ffn_b1,
                                                                      ffh, M, FFD, DD);
    // 11. FFN layer 2
    gemm_mfma_kernel<0, bf16, bf16><<<dim3(4, MT), 256, 0, stream>>>(ffh, w_ffn2, ffn_b2,
                                                                     tmp, M, DD, FFD);
    // 12. LN3 -> fp32 output
    add_ln_kernel<bf16, float><<<M, 256, 0, stream>>>(t2n, tmp, norm3_s, norm3_b,
                                                      (float*)d_out);
}